// Round 1
// baseline (361.126 us; speedup 1.0000x reference)
//
#include <hip/hip_runtime.h>

// Problem constants (match reference setup_inputs / module constants)
#define BB 16
#define LL 4096
#define GG 256
#define RR 84
#define WW 169      // 2*R+1
#define DD 12
#define VOCAB 25    // 2*D+1

// Output element offsets (int32 elements, concat in return order)
#define S_L2L (BB * LL * WW)   // 11,075,584
#define S_G2G (BB * GG * GG)   //  1,048,576
#define S_L2G (BB * LL * GG)   // 16,777,216
#define S_G2L (BB * GG * LL)   // 16,777,216
#define OFF0 0
#define OFF1 (OFF0 + S_L2L)
#define OFF2 (OFF1 + S_G2G)
#define OFF3 (OFF2 + S_L2G)
#define OFF4 (OFF3 + S_G2L)
#define OFF5 (OFF4 + S_L2L)
#define OFF6 (OFF5 + S_G2G)
#define OFF7 (OFF6 + S_L2G)

// Fused writer: 1024 output elements (per stream) per 256-thread block,
// 4 consecutive elements (one int4) per thread per stream.
#define NB_L2L (S_L2L / 1024)   // 10816
#define NB_G2G (S_G2G / 1024)   //  1024
#define NB_L2G (S_L2G / 1024)   // 16384
#define NB_G2L (S_G2L / 1024)   // 16384
#define NB_TOTAL (NB_L2L + NB_G2G + NB_L2G + NB_G2L)  // 44608

// Non-temporal int4 store: output is write-once, never re-read by us.
// Bypass L2 so the seg/pid read tables stay cached.
typedef int v4i __attribute__((ext_vector_type(4)));
static __device__ __forceinline__ void nt_store4(int* p, int a, int b, int c, int d) {
    v4i v = {a, b, c, d};
    __builtin_nontemporal_store(v, (v4i*)p);
}

// -------- suffix-cumsum kernel: one block (256 threads) per batch --------
// Wave-shuffle scans, single barrier (was 32 barriers of Hillis-Steele).
__global__ __launch_bounds__(256) void scan_kernel(
        const int* __restrict__ long_bp,
        const int* __restrict__ glob_bp,
        int* __restrict__ long_seg,
        int* __restrict__ glob_seg) {
    const int b = blockIdx.x;
    const int t = threadIdx.x;          // 256 threads
    const int lane = t & 63;
    const int wv = t >> 6;              // 4 waves
    __shared__ int wsA[4];              // long wave sums
    __shared__ int wsB[4];              // glob wave sums

    // ---- long: 16 consecutive elems per thread, vectorized ----
    const int4* bp4 = (const int4*)(long_bp + b * LL) + t * 4;
    int4 v[4];
#pragma unroll
    for (int j = 0; j < 4; ++j) v[j] = bp4[j];
    int vals[16];
#pragma unroll
    for (int j = 0; j < 4; ++j) {
        vals[4*j+0] = v[j].x; vals[4*j+1] = v[j].y;
        vals[4*j+2] = v[j].z; vals[4*j+3] = v[j].w;
    }
    int s = 0;
#pragma unroll
    for (int j = 0; j < 16; ++j) s += vals[j];

    // inclusive wave scan of per-thread sums
    int sc = s;
#pragma unroll
    for (int off = 1; off < 64; off <<= 1) {
        int n = __shfl_up(sc, off, 64);
        if (lane >= off) sc += n;
    }
    if (lane == 63) wsA[wv] = sc;

    // ---- glob: 1 elem per thread, scan overlapped with long phase ----
    const int gv = glob_bp[b * GG + t];
    int gsc = gv;
#pragma unroll
    for (int off = 1; off < 64; off <<= 1) {
        int n = __shfl_up(gsc, off, 64);
        if (lane >= off) gsc += n;
    }
    if (lane == 63) wsB[wv] = gsc;

    __syncthreads();   // the only barrier

    int beforeA = 0, beforeB = 0;
#pragma unroll
    for (int w = 0; w < 4; ++w) {
        if (w < wv) { beforeA += wsA[w]; beforeB += wsB[w]; }
    }
    const int totalA = wsA[0] + wsA[1] + wsA[2] + wsA[3];
    const int totalB = wsB[0] + wsB[1] + wsB[2] + wsB[3];

    // suffix sum incl. element = total - exclusive_prefix(element)
    int run = beforeA + (sc - s);        // exclusive prefix at chunk start
    int4* seg4 = (int4*)(long_seg + b * LL) + t * 4;
#pragma unroll
    for (int j = 0; j < 4; ++j) {
        int4 o;
        o.x = totalA - run; run += vals[4*j+0];
        o.y = totalA - run; run += vals[4*j+1];
        o.z = totalA - run; run += vals[4*j+2];
        o.w = totalA - run; run += vals[4*j+3];
        seg4[j] = o;                     // normal store: re-read by fused_writer
    }
    glob_seg[b * GG + t] = totalB - (beforeB + (gsc - gv));
}

// -------- fused writer: all 4 (mask, rel) pairs, NT int4 stores -----------
__global__ __launch_bounds__(256) void fused_writer(
        const int* __restrict__ long_seg,
        const int* __restrict__ long_pid,
        const int* __restrict__ glob_seg,
        int* __restrict__ out) {
    const int blk = blockIdx.x;
    const int tid = threadIdx.x;

    if (blk < NB_L2L) {
        // ---- l2l: flat over (b*L + i) * 169 + k ----
        unsigned f = (unsigned)blk * 1024u + (unsigned)tid * 4u;
        unsigned row = f / (unsigned)WW;          // b*L + i
        int k = (int)(f - row * (unsigned)WW);
        int i = (int)(row & (LL - 1));
        unsigned base = row - (unsigned)i;        // b*L
        int segi = long_seg[row];
        int m[4], r[4];
#pragma unroll
        for (int e = 0; e < 4; ++e) {
            const int j = i + k - RR;
            int msk = 0;
            if (j >= 0 && j < LL) msk = (long_seg[base + (unsigned)j] == segi) ? 1 : 0;
            int c = k - RR;
            c = c < -DD ? -DD : (c > DD ? DD : c);
            r[e] = (c >= 0) ? c : (DD - c);
            m[e] = msk;
            if (e < 3) {
                if (++k == WW) {
                    k = 0; ++row;
                    i = (int)(row & (LL - 1));
                    base = row - (unsigned)i;
                    segi = long_seg[row];
                }
            }
        }
        nt_store4(out + OFF0 + f, m[0], m[1], m[2], m[3]);
        nt_store4(out + OFF4 + f, r[0], r[1], r[2], r[3]);

    } else if (blk < NB_L2L + NB_G2G) {
        // ---- g2g: flat over (b*G + g) * G + h ----
        const int blk2 = blk - NB_L2L;
        const unsigned f = (unsigned)blk2 * 1024u + (unsigned)tid * 4u;
        const int h0 = (int)(f & (GG - 1));       // multiple of 4
        const unsigned row = f >> 8;              // b*G + g
        const int g = (int)(row & (GG - 1));
        const int segg = glob_seg[row];
        const int tokg = segg > 0 ? 1 : 0;
        const int4 sh = *(const int4*)(glob_seg + (row - (unsigned)g) + (unsigned)h0);
        const int sgh[4] = {sh.x, sh.y, sh.z, sh.w};
        int m[4], r[4];
#pragma unroll
        for (int e = 0; e < 4; ++e) {
            const int tokh = sgh[e] > 0 ? 1 : 0;
            int c = (h0 + e) - g;
            c = c < -DD ? -DD : (c > DD ? DD : c);
            const int r0 = (c >= 0) ? c : (DD - c);
            m[e] = (tokg == tokh) ? 1 : 0;
            r[e] = (segg == sgh[e]) ? r0 : (VOCAB + 2);
        }
        nt_store4(out + OFF1 + f, m[0], m[1], m[2], m[3]);
        nt_store4(out + OFF5 + f, r[0], r[1], r[2], r[3]);

    } else if (blk < NB_L2L + NB_G2G + NB_L2G) {
        // ---- l2g: flat over (b*L + i) * G + g ----
        const int blk3 = blk - (NB_L2L + NB_G2G);
        const unsigned f = (unsigned)blk3 * 1024u + (unsigned)tid * 4u;
        const int g0 = (int)(f & (GG - 1));       // multiple of 4
        const unsigned row = f >> 8;              // b*L + i
        const int b = (int)(row >> 12);
        const int tokl = long_seg[row] > 0 ? 1 : 0;
        const int pid = long_pid[row];
        const int4 sg = *(const int4*)(glob_seg + b * GG + g0);
        const int sgv[4] = {sg.x, sg.y, sg.z, sg.w};
        int m[4], r[4];
#pragma unroll
        for (int e = 0; e < 4; ++e) {
            const int tokg = sgv[e] > 0 ? 1 : 0;
            const int eq = (pid == (g0 + e)) ? 1 : 0;
            m[e] = (tokl == tokg) ? eq : 0;
            r[e] = eq + VOCAB;
        }
        nt_store4(out + OFF2 + f, m[0], m[1], m[2], m[3]);
        nt_store4(out + OFF6 + f, r[0], r[1], r[2], r[3]);

    } else {
        // ---- g2l: flat over (b*G + g) * L + i ----
        const int blk4 = blk - (NB_L2L + NB_G2G + NB_L2G);
        const unsigned f = (unsigned)blk4 * 1024u + (unsigned)tid * 4u;
        const int i0 = (int)(f & (LL - 1));       // multiple of 4
        const unsigned row = f >> 12;             // b*G + g
        const int g = (int)(row & (GG - 1));
        const int b = (int)(row >> 8);
        const int tokg = glob_seg[row] > 0 ? 1 : 0;
        const int4 pid4 = *(const int4*)(long_pid + b * LL + i0);
        const int4 seg4 = *(const int4*)(long_seg + b * LL + i0);
        const int pidv[4] = {pid4.x, pid4.y, pid4.z, pid4.w};
        const int segv[4] = {seg4.x, seg4.y, seg4.z, seg4.w};
        const int gz = (g == 0) ? 1 : 0;
        int m[4], r[4];
#pragma unroll
        for (int e = 0; e < 4; ++e) {
            const int tokl = segv[e] > 0 ? 1 : 0;
            const int eq = (g == pidv[e]) ? 1 : 0;
            const int allow = eq | gz;
            m[e] = (tokl == tokg) ? allow : 0;
            r[e] = eq + VOCAB;
        }
        nt_store4(out + OFF3 + f, m[0], m[1], m[2], m[3]);
        nt_store4(out + OFF7 + f, r[0], r[1], r[2], r[3]);
    }
}

extern "C" void kernel_launch(void* const* d_in, const int* in_sizes, int n_in,
                              void* d_out, int out_size, void* d_ws, size_t ws_size,
                              hipStream_t stream) {
    const int* long_bp  = (const int*)d_in[0];  // (B, L)
    const int* long_pid = (const int*)d_in[1];  // (B, L)
    const int* glob_bp  = (const int*)d_in[2];  // (B, G)
    int* out = (int*)d_out;

    // workspace: long_seg (B*L) then glob_seg (B*G) — 278,528 bytes
    int* long_seg = (int*)d_ws;
    int* glob_seg = long_seg + BB * LL;

    scan_kernel<<<BB, 256, 0, stream>>>(long_bp, glob_bp, long_seg, glob_seg);
    fused_writer<<<NB_TOTAL, 256, 0, stream>>>(long_seg, long_pid, glob_seg, out);
}